// Round 1
// baseline (3950.414 us; speedup 1.0000x reference)
//
#include <hip/hip_runtime.h>
#include <math.h>

#define N_NODES 100000
#define N_EDGES 3200000
#define NFEAT   512
#define HIDDEN  256
#define NCLASS  64
#define K_HOPS  10

// ---------------------------------------------------------------------------
// Graph preprocessing: counting sort of edges by target node (CSR build)
// ---------------------------------------------------------------------------

__global__ void init_kernel(int* __restrict__ degi, int* __restrict__ cursor, int n) {
    int i = blockIdx.x * blockDim.x + threadIdx.x;
    if (i < n) { degi[i] = 1; cursor[i] = 0; }  // deg starts at 1 (self-loop)
}

__global__ void count_kernel(const int* __restrict__ col, int* __restrict__ degi, int e) {
    int i = blockIdx.x * blockDim.x + threadIdx.x;
    if (i < e) atomicAdd(&degi[col[i]], 1);
}

__global__ void dinv_kernel(const int* __restrict__ degi, float* __restrict__ dinv, int n) {
    int i = blockIdx.x * blockDim.x + threadIdx.x;
    if (i < n) dinv[i] = rsqrtf((float)degi[i]);  // deg >= 1 always (self-loop)
}

// Single-block scan over per-node REAL edge counts (degi - 1) -> CSR offsets.
__global__ void scan_kernel(const int* __restrict__ degi, int* __restrict__ offs, int n) {
    __shared__ int part[1024];
    int tid = threadIdx.x;
    int chunk = (n + 1023) / 1024;
    int beg = tid * chunk;
    int end = min(beg + chunk, n);
    int s = 0;
    for (int i = beg; i < end; ++i) s += degi[i] - 1;
    part[tid] = s;
    __syncthreads();
    // Hillis-Steele inclusive scan over 1024 partials
    for (int d = 1; d < 1024; d <<= 1) {
        int v = (tid >= d) ? part[tid - d] : 0;
        __syncthreads();
        part[tid] += v;
        __syncthreads();
    }
    int run = (tid > 0) ? part[tid - 1] : 0;
    for (int i = beg; i < end; ++i) { offs[i] = run; run += degi[i] - 1; }
    if (tid == 1023) offs[n] = part[1023];  // == N_EDGES
}

__global__ void scatter_kernel(const int* __restrict__ row, const int* __restrict__ col,
                               const float* __restrict__ dinv,
                               const int* __restrict__ offs, int* __restrict__ cursor,
                               int* __restrict__ src_s, float* __restrict__ w_s, int e) {
    int i = blockIdx.x * blockDim.x + threadIdx.x;
    if (i < e) {
        int c = col[i];
        int r = row[i];
        int p = offs[c] + atomicAdd(&cursor[c], 1);
        src_s[p] = r;
        w_s[p]   = dinv[r] * dinv[c];
    }
}

// ---------------------------------------------------------------------------
// MLP: fp32 LDS-tiled SGEMM, 64x64 block tile, 4x4 per thread, BK=16
// ---------------------------------------------------------------------------

// C[M,HIDDEN] = relu(A[M,NFEAT] @ B[NFEAT,HIDDEN] + bias)
__global__ __launch_bounds__(256) void sgemm_relu(const float* __restrict__ A,
                                                  const float* __restrict__ B,
                                                  const float* __restrict__ bias,
                                                  float* __restrict__ C, int M) {
    const int K = NFEAT, N = HIDDEN;
    __shared__ float As[16][65];   // [k][m], padded
    __shared__ float Bs[16][64];   // [k][n]
    int tid = threadIdx.x;
    int tx = tid & 15, ty = tid >> 4;
    int m0 = blockIdx.x * 64, n0 = blockIdx.y * 64;
    int a_m = tid >> 2;          // 0..63
    int a_k = (tid & 3) << 2;    // 0,4,8,12
    int b_k = tid >> 4;          // 0..15
    int b_n = (tid & 15) << 2;   // 0..60
    float acc[4][4] = {};
    for (int k0 = 0; k0 < K; k0 += 16) {
        float4 av = make_float4(0.f, 0.f, 0.f, 0.f);
        int arow = m0 + a_m;
        if (arow < M) av = *reinterpret_cast<const float4*>(A + (size_t)arow * K + k0 + a_k);
        As[a_k + 0][a_m] = av.x; As[a_k + 1][a_m] = av.y;
        As[a_k + 2][a_m] = av.z; As[a_k + 3][a_m] = av.w;
        float4 bv = *reinterpret_cast<const float4*>(B + (size_t)(k0 + b_k) * N + n0 + b_n);
        *reinterpret_cast<float4*>(&Bs[b_k][b_n]) = bv;
        __syncthreads();
#pragma unroll
        for (int kk = 0; kk < 16; ++kk) {
            float a[4], b[4];
#pragma unroll
            for (int i = 0; i < 4; ++i) a[i] = As[kk][ty * 4 + i];
#pragma unroll
            for (int j = 0; j < 4; ++j) b[j] = Bs[kk][tx * 4 + j];
#pragma unroll
            for (int i = 0; i < 4; ++i)
#pragma unroll
                for (int j = 0; j < 4; ++j) acc[i][j] += a[i] * b[j];
        }
        __syncthreads();
    }
#pragma unroll
    for (int i = 0; i < 4; ++i) {
        int m = m0 + ty * 4 + i;
        if (m >= M) continue;
        float4 v;
        v.x = fmaxf(acc[i][0] + bias[n0 + tx * 4 + 0], 0.f);
        v.y = fmaxf(acc[i][1] + bias[n0 + tx * 4 + 1], 0.f);
        v.z = fmaxf(acc[i][2] + bias[n0 + tx * 4 + 2], 0.f);
        v.w = fmaxf(acc[i][3] + bias[n0 + tx * 4 + 3], 0.f);
        *reinterpret_cast<float4*>(C + (size_t)m * N + n0 + tx * 4) = v;
    }
}

// h0[M,NCLASS] = A[M,HIDDEN] @ B[HIDDEN,NCLASS] + bias ; hidden = temp[0]*h0
__global__ __launch_bounds__(256) void sgemm_dual(const float* __restrict__ A,
                                                  const float* __restrict__ B,
                                                  const float* __restrict__ bias,
                                                  float* __restrict__ h0,
                                                  float* __restrict__ hidden,
                                                  const float* __restrict__ temp, int M) {
    const int K = HIDDEN, N = NCLASS;
    __shared__ float As[16][65];
    __shared__ float Bs[16][64];
    int tid = threadIdx.x;
    int tx = tid & 15, ty = tid >> 4;
    int m0 = blockIdx.x * 64;
    int a_m = tid >> 2;
    int a_k = (tid & 3) << 2;
    int b_k = tid >> 4;
    int b_n = (tid & 15) << 2;
    float acc[4][4] = {};
    for (int k0 = 0; k0 < K; k0 += 16) {
        float4 av = make_float4(0.f, 0.f, 0.f, 0.f);
        int arow = m0 + a_m;
        if (arow < M) av = *reinterpret_cast<const float4*>(A + (size_t)arow * K + k0 + a_k);
        As[a_k + 0][a_m] = av.x; As[a_k + 1][a_m] = av.y;
        As[a_k + 2][a_m] = av.z; As[a_k + 3][a_m] = av.w;
        float4 bv = *reinterpret_cast<const float4*>(B + (size_t)(k0 + b_k) * N + b_n);
        *reinterpret_cast<float4*>(&Bs[b_k][b_n]) = bv;
        __syncthreads();
#pragma unroll
        for (int kk = 0; kk < 16; ++kk) {
            float a[4], b[4];
#pragma unroll
            for (int i = 0; i < 4; ++i) a[i] = As[kk][ty * 4 + i];
#pragma unroll
            for (int j = 0; j < 4; ++j) b[j] = Bs[kk][tx * 4 + j];
#pragma unroll
            for (int i = 0; i < 4; ++i)
#pragma unroll
                for (int j = 0; j < 4; ++j) acc[i][j] += a[i] * b[j];
        }
        __syncthreads();
    }
    float t0 = temp[0];
#pragma unroll
    for (int i = 0; i < 4; ++i) {
        int m = m0 + ty * 4 + i;
        if (m >= M) continue;
        float4 v;
        v.x = acc[i][0] + bias[tx * 4 + 0];
        v.y = acc[i][1] + bias[tx * 4 + 1];
        v.z = acc[i][2] + bias[tx * 4 + 2];
        v.w = acc[i][3] + bias[tx * 4 + 3];
        *reinterpret_cast<float4*>(h0 + (size_t)m * N + tx * 4) = v;
        float4 hv = make_float4(t0 * v.x, t0 * v.y, t0 * v.z, t0 * v.w);
        *reinterpret_cast<float4*>(hidden + (size_t)m * N + tx * 4) = hv;
    }
}

// ---------------------------------------------------------------------------
// GPR propagation: one 64-lane wave per node, lane = feature. No atomics.
// hout[c] = dinv[c]^2 * hin[c] + sum_{e in CSR[c]} w[e] * hin[src[e]]
// hidden[c] += temp[k] * hout[c]
// ---------------------------------------------------------------------------
__global__ __launch_bounds__(256) void propagate_kernel(const int* __restrict__ offs,
                                                        const int* __restrict__ src,
                                                        const float* __restrict__ w,
                                                        const float* __restrict__ dinv,
                                                        const float* __restrict__ hin,
                                                        float* __restrict__ hout,
                                                        float* __restrict__ hidden,
                                                        const float* __restrict__ temp,
                                                        int kidx, int n) {
    int node = (blockIdx.x * blockDim.x + threadIdx.x) >> 6;
    int lane = threadIdx.x & 63;
    if (node >= n) return;
    float tk = temp[kidx];
    int beg = offs[node], end = offs[node + 1];
    float di = dinv[node];
    float acc = di * di * hin[(size_t)node * 64 + lane];
    for (int e = beg; e < end; ++e) {
        int s = src[e];
        float ww = w[e];
        acc += ww * hin[(size_t)s * 64 + lane];
    }
    hout[(size_t)node * 64 + lane] = acc;
    hidden[(size_t)node * 64 + lane] += tk * acc;
}

// ---------------------------------------------------------------------------
// log_softmax over 64 classes: one wave per node
// ---------------------------------------------------------------------------
__global__ __launch_bounds__(256) void logsoftmax_kernel(const float* __restrict__ hidden,
                                                         float* __restrict__ out, int n) {
    int node = (blockIdx.x * blockDim.x + threadIdx.x) >> 6;
    int lane = threadIdx.x & 63;
    if (node >= n) return;
    float v = hidden[(size_t)node * 64 + lane];
    float m = v;
#pragma unroll
    for (int o = 32; o > 0; o >>= 1) m = fmaxf(m, __shfl_xor(m, o, 64));
    float ex = expf(v - m);
    float s = ex;
#pragma unroll
    for (int o = 32; o > 0; o >>= 1) s += __shfl_xor(s, o, 64);
    out[(size_t)node * 64 + lane] = v - m - logf(s);
}

// ---------------------------------------------------------------------------

extern "C" void kernel_launch(void* const* d_in, const int* in_sizes, int n_in,
                              void* d_out, int out_size, void* d_ws, size_t ws_size,
                              hipStream_t stream) {
    const float* x    = (const float*)d_in[0];
    const int*   ei   = (const int*)d_in[1];
    const int*   row  = ei;             // source nodes
    const int*   col  = ei + N_EDGES;   // target nodes
    const float* W1   = (const float*)d_in[2];
    const float* b1   = (const float*)d_in[3];
    const float* W2   = (const float*)d_in[4];
    const float* b2   = (const float*)d_in[5];
    const float* temp = (const float*)d_in[6];
    float*       out  = (float*)d_out;

    char* ws = (char*)d_ws;
    size_t off = 0;
    auto alloc = [&](size_t bytes) -> void* {
        void* p = ws + off;
        off += (bytes + 255) & ~(size_t)255;
        return p;
    };
    int*   degi   = (int*)  alloc((size_t)N_NODES * 4);
    float* dinv   = (float*)alloc((size_t)N_NODES * 4);
    int*   offs   = (int*)  alloc((size_t)(N_NODES + 1) * 4);
    int*   cursor = (int*)  alloc((size_t)N_NODES * 4);
    int*   src_s  = (int*)  alloc((size_t)N_EDGES * 4);
    float* w_s    = (float*)alloc((size_t)N_EDGES * 4);
    float* h_mlp  = (float*)alloc((size_t)N_NODES * HIDDEN * 4);
    float* h_a    = (float*)alloc((size_t)N_NODES * NCLASS * 4);
    float* h_b    = (float*)alloc((size_t)N_NODES * NCLASS * 4);
    float* hidden = (float*)alloc((size_t)N_NODES * NCLASS * 4);

    // --- graph preprocessing ---
    init_kernel<<<(N_NODES + 255) / 256, 256, 0, stream>>>(degi, cursor, N_NODES);
    count_kernel<<<(N_EDGES + 255) / 256, 256, 0, stream>>>(col, degi, N_EDGES);
    dinv_kernel<<<(N_NODES + 255) / 256, 256, 0, stream>>>(degi, dinv, N_NODES);
    scan_kernel<<<1, 1024, 0, stream>>>(degi, offs, N_NODES);
    scatter_kernel<<<(N_EDGES + 255) / 256, 256, 0, stream>>>(row, col, dinv, offs, cursor,
                                                              src_s, w_s, N_EDGES);

    // --- MLP ---
    dim3 g1((N_NODES + 63) / 64, HIDDEN / 64);
    sgemm_relu<<<g1, 256, 0, stream>>>(x, W1, b1, h_mlp, N_NODES);
    dim3 g2((N_NODES + 63) / 64, 1);
    sgemm_dual<<<g2, 256, 0, stream>>>(h_mlp, W2, b2, h_a, hidden, temp, N_NODES);

    // --- GPR propagation: 10 hops ---
    int pgrid = (N_NODES * 64 + 255) / 256;
    for (int k = 0; k < K_HOPS; ++k) {
        float* hi = (k & 1) ? h_b : h_a;
        float* ho = (k & 1) ? h_a : h_b;
        propagate_kernel<<<pgrid, 256, 0, stream>>>(offs, src_s, w_s, dinv, hi, ho, hidden,
                                                    temp, k + 1, N_NODES);
    }

    // --- log_softmax ---
    logsoftmax_kernel<<<pgrid, 256, 0, stream>>>(hidden, out, N_NODES);
}

// Round 2
// 2191.097 us; speedup vs baseline: 1.8029x; 1.8029x over previous
//
#include <hip/hip_runtime.h>
#include <hip/hip_bf16.h>
#include <math.h>

#define N_NODES 100000
#define N_EDGES 3200000
#define NFEAT   512
#define HIDDEN  256
#define NCLASS  64
#define K_HOPS  10

typedef unsigned short bfbits;

__device__ __forceinline__ float bf2f(bfbits u) {
    union { unsigned int i; float f; } v; v.i = ((unsigned int)u) << 16; return v.f;
}
__device__ __forceinline__ bfbits f2bf(float f) {
    union { float f; unsigned int i; } v; v.f = f;
    unsigned int b = v.i + 0x7FFFu + ((v.i >> 16) & 1u);   // round-to-nearest-even
    return (bfbits)(b >> 16);
}

// ---------------------------------------------------------------------------
// Graph preprocessing: counting sort of edges by target node (CSR build)
// ---------------------------------------------------------------------------

__global__ void init_kernel(int* __restrict__ degi, int* __restrict__ cursor, int n) {
    int i = blockIdx.x * blockDim.x + threadIdx.x;
    if (i < n) { degi[i] = 1; cursor[i] = 0; }  // deg starts at 1 (self-loop)
}

__global__ void count_kernel(const int* __restrict__ col, int* __restrict__ degi, int e) {
    int i = blockIdx.x * blockDim.x + threadIdx.x;
    if (i < e) atomicAdd(&degi[col[i]], 1);
}

__global__ void dinv_kernel(const int* __restrict__ degi, float* __restrict__ dinv, int n) {
    int i = blockIdx.x * blockDim.x + threadIdx.x;
    if (i < n) dinv[i] = rsqrtf((float)degi[i]);  // deg >= 1 always (self-loop)
}

// Single-block scan over per-node REAL edge counts (degi - 1) -> CSR offsets.
__global__ void scan_kernel(const int* __restrict__ degi, int* __restrict__ offs, int n) {
    __shared__ int part[1024];
    int tid = threadIdx.x;
    int chunk = (n + 1023) / 1024;
    int beg = tid * chunk;
    int end = min(beg + chunk, n);
    int s = 0;
    for (int i = beg; i < end; ++i) s += degi[i] - 1;
    part[tid] = s;
    __syncthreads();
    for (int d = 1; d < 1024; d <<= 1) {
        int v = (tid >= d) ? part[tid - d] : 0;
        __syncthreads();
        part[tid] += v;
        __syncthreads();
    }
    int run = (tid > 0) ? part[tid - 1] : 0;
    for (int i = beg; i < end; ++i) { offs[i] = run; run += degi[i] - 1; }
    if (tid == 1023) offs[n] = part[1023];  // == N_EDGES
}

// edges[p] = (src, bits(w)) packed so the hop loop does ONE 8B broadcast load/edge
__global__ void scatter_kernel(const int* __restrict__ row, const int* __restrict__ col,
                               const float* __restrict__ dinv,
                               const int* __restrict__ offs, int* __restrict__ cursor,
                               int2* __restrict__ edges, int e) {
    int i = blockIdx.x * blockDim.x + threadIdx.x;
    if (i < e) {
        int c = col[i];
        int r = row[i];
        int p = offs[c] + atomicAdd(&cursor[c], 1);
        edges[p] = make_int2(r, __float_as_int(dinv[r] * dinv[c]));
    }
}

// ---------------------------------------------------------------------------
// MLP: fp32 LDS-tiled SGEMM, 64x64 block tile, 4x4 per thread, BK=16
// ---------------------------------------------------------------------------

__global__ __launch_bounds__(256) void sgemm_relu(const float* __restrict__ A,
                                                  const float* __restrict__ B,
                                                  const float* __restrict__ bias,
                                                  float* __restrict__ C, int M) {
    const int K = NFEAT, N = HIDDEN;
    __shared__ float As[16][65];
    __shared__ float Bs[16][64];
    int tid = threadIdx.x;
    int tx = tid & 15, ty = tid >> 4;
    int m0 = blockIdx.x * 64, n0 = blockIdx.y * 64;
    int a_m = tid >> 2;
    int a_k = (tid & 3) << 2;
    int b_k = tid >> 4;
    int b_n = (tid & 15) << 2;
    float acc[4][4] = {};
    for (int k0 = 0; k0 < K; k0 += 16) {
        float4 av = make_float4(0.f, 0.f, 0.f, 0.f);
        int arow = m0 + a_m;
        if (arow < M) av = *reinterpret_cast<const float4*>(A + (size_t)arow * K + k0 + a_k);
        As[a_k + 0][a_m] = av.x; As[a_k + 1][a_m] = av.y;
        As[a_k + 2][a_m] = av.z; As[a_k + 3][a_m] = av.w;
        float4 bv = *reinterpret_cast<const float4*>(B + (size_t)(k0 + b_k) * N + n0 + b_n);
        *reinterpret_cast<float4*>(&Bs[b_k][b_n]) = bv;
        __syncthreads();
#pragma unroll
        for (int kk = 0; kk < 16; ++kk) {
            float a[4], b[4];
#pragma unroll
            for (int i = 0; i < 4; ++i) a[i] = As[kk][ty * 4 + i];
#pragma unroll
            for (int j = 0; j < 4; ++j) b[j] = Bs[kk][tx * 4 + j];
#pragma unroll
            for (int i = 0; i < 4; ++i)
#pragma unroll
                for (int j = 0; j < 4; ++j) acc[i][j] += a[i] * b[j];
        }
        __syncthreads();
    }
#pragma unroll
    for (int i = 0; i < 4; ++i) {
        int m = m0 + ty * 4 + i;
        if (m >= M) continue;
        float4 v;
        v.x = fmaxf(acc[i][0] + bias[n0 + tx * 4 + 0], 0.f);
        v.y = fmaxf(acc[i][1] + bias[n0 + tx * 4 + 1], 0.f);
        v.z = fmaxf(acc[i][2] + bias[n0 + tx * 4 + 2], 0.f);
        v.w = fmaxf(acc[i][3] + bias[n0 + tx * 4 + 3], 0.f);
        *reinterpret_cast<float4*>(C + (size_t)m * N + n0 + tx * 4) = v;
    }
}

// h0(bf16)[M,NCLASS] = A @ W2 + b2 ; hidden(fp32) = temp[0]*h0
__global__ __launch_bounds__(256) void sgemm_dual(const float* __restrict__ A,
                                                  const float* __restrict__ B,
                                                  const float* __restrict__ bias,
                                                  bfbits* __restrict__ h0,
                                                  float* __restrict__ hidden,
                                                  const float* __restrict__ temp, int M) {
    const int K = HIDDEN, N = NCLASS;
    __shared__ float As[16][65];
    __shared__ float Bs[16][64];
    int tid = threadIdx.x;
    int tx = tid & 15, ty = tid >> 4;
    int m0 = blockIdx.x * 64;
    int a_m = tid >> 2;
    int a_k = (tid & 3) << 2;
    int b_k = tid >> 4;
    int b_n = (tid & 15) << 2;
    float acc[4][4] = {};
    for (int k0 = 0; k0 < K; k0 += 16) {
        float4 av = make_float4(0.f, 0.f, 0.f, 0.f);
        int arow = m0 + a_m;
        if (arow < M) av = *reinterpret_cast<const float4*>(A + (size_t)arow * K + k0 + a_k);
        As[a_k + 0][a_m] = av.x; As[a_k + 1][a_m] = av.y;
        As[a_k + 2][a_m] = av.z; As[a_k + 3][a_m] = av.w;
        float4 bv = *reinterpret_cast<const float4*>(B + (size_t)(k0 + b_k) * N + b_n);
        *reinterpret_cast<float4*>(&Bs[b_k][b_n]) = bv;
        __syncthreads();
#pragma unroll
        for (int kk = 0; kk < 16; ++kk) {
            float a[4], b[4];
#pragma unroll
            for (int i = 0; i < 4; ++i) a[i] = As[kk][ty * 4 + i];
#pragma unroll
            for (int j = 0; j < 4; ++j) b[j] = Bs[kk][tx * 4 + j];
#pragma unroll
            for (int i = 0; i < 4; ++i)
#pragma unroll
                for (int j = 0; j < 4; ++j) acc[i][j] += a[i] * b[j];
        }
        __syncthreads();
    }
    float t0 = temp[0];
#pragma unroll
    for (int i = 0; i < 4; ++i) {
        int m = m0 + ty * 4 + i;
        if (m >= M) continue;
        float4 v;
        v.x = acc[i][0] + bias[tx * 4 + 0];
        v.y = acc[i][1] + bias[tx * 4 + 1];
        v.z = acc[i][2] + bias[tx * 4 + 2];
        v.w = acc[i][3] + bias[tx * 4 + 3];
        ushort4 hb;
        hb.x = f2bf(v.x); hb.y = f2bf(v.y); hb.z = f2bf(v.z); hb.w = f2bf(v.w);
        *reinterpret_cast<ushort4*>(h0 + (size_t)m * N + tx * 4) = hb;
        float4 hv = make_float4(t0 * v.x, t0 * v.y, t0 * v.z, t0 * v.w);
        *reinterpret_cast<float4*>(hidden + (size_t)m * N + tx * 4) = hv;
    }
}

// ---------------------------------------------------------------------------
// GPR propagation: one 64-lane wave per node, lane = feature, bf16 h state.
// Edge loop unrolled x4 -> 4 independent 128B gathers in flight per wave.
// ---------------------------------------------------------------------------
__global__ __launch_bounds__(256) void propagate_kernel(const int* __restrict__ offs,
                                                        const int2* __restrict__ edges,
                                                        const float* __restrict__ dinv,
                                                        const bfbits* __restrict__ hin,
                                                        bfbits* __restrict__ hout,
                                                        float* __restrict__ hidden,
                                                        const float* __restrict__ temp,
                                                        int kidx, int n) {
    int node = (blockIdx.x * blockDim.x + threadIdx.x) >> 6;
    int lane = threadIdx.x & 63;
    if (node >= n) return;
    float tk = temp[kidx];
    int beg = offs[node], end = offs[node + 1];
    float di = dinv[node];
    float acc = di * di * bf2f(hin[(size_t)node * 64 + lane]);
    int e = beg;
    for (; e + 4 <= end; e += 4) {
        int2 e0 = edges[e + 0];
        int2 e1 = edges[e + 1];
        int2 e2 = edges[e + 2];
        int2 e3 = edges[e + 3];
        bfbits u0 = hin[(size_t)e0.x * 64 + lane];
        bfbits u1 = hin[(size_t)e1.x * 64 + lane];
        bfbits u2 = hin[(size_t)e2.x * 64 + lane];
        bfbits u3 = hin[(size_t)e3.x * 64 + lane];
        acc += __int_as_float(e0.y) * bf2f(u0);
        acc += __int_as_float(e1.y) * bf2f(u1);
        acc += __int_as_float(e2.y) * bf2f(u2);
        acc += __int_as_float(e3.y) * bf2f(u3);
    }
    for (; e < end; ++e) {
        int2 ed = edges[e];
        acc += __int_as_float(ed.y) * bf2f(hin[(size_t)ed.x * 64 + lane]);
    }
    hout[(size_t)node * 64 + lane] = f2bf(acc);
    hidden[(size_t)node * 64 + lane] += tk * acc;
}

// ---------------------------------------------------------------------------
// log_softmax over 64 classes: one wave per node
// ---------------------------------------------------------------------------
__global__ __launch_bounds__(256) void logsoftmax_kernel(const float* __restrict__ hidden,
                                                         float* __restrict__ out, int n) {
    int node = (blockIdx.x * blockDim.x + threadIdx.x) >> 6;
    int lane = threadIdx.x & 63;
    if (node >= n) return;
    float v = hidden[(size_t)node * 64 + lane];
    float m = v;
#pragma unroll
    for (int o = 32; o > 0; o >>= 1) m = fmaxf(m, __shfl_xor(m, o, 64));
    float ex = expf(v - m);
    float s = ex;
#pragma unroll
    for (int o = 32; o > 0; o >>= 1) s += __shfl_xor(s, o, 64);
    out[(size_t)node * 64 + lane] = v - m - logf(s);
}

// ---------------------------------------------------------------------------

extern "C" void kernel_launch(void* const* d_in, const int* in_sizes, int n_in,
                              void* d_out, int out_size, void* d_ws, size_t ws_size,
                              hipStream_t stream) {
    const float* x    = (const float*)d_in[0];
    const int*   ei   = (const int*)d_in[1];
    const int*   row  = ei;             // source nodes
    const int*   col  = ei + N_EDGES;   // target nodes
    const float* W1   = (const float*)d_in[2];
    const float* b1   = (const float*)d_in[3];
    const float* W2   = (const float*)d_in[4];
    const float* b2   = (const float*)d_in[5];
    const float* temp = (const float*)d_in[6];
    float*       out  = (float*)d_out;

    char* ws = (char*)d_ws;
    size_t off = 0;
    auto alloc = [&](size_t bytes) -> void* {
        void* p = ws + off;
        off += (bytes + 255) & ~(size_t)255;
        return p;
    };
    int*    degi   = (int*)   alloc((size_t)N_NODES * 4);
    float*  dinv   = (float*) alloc((size_t)N_NODES * 4);
    int*    offs   = (int*)   alloc((size_t)(N_NODES + 1) * 4);
    int*    cursor = (int*)   alloc((size_t)N_NODES * 4);
    int2*   edges  = (int2*)  alloc((size_t)N_EDGES * 8);
    float*  h_mlp  = (float*) alloc((size_t)N_NODES * HIDDEN * 4);
    bfbits* h_a    = (bfbits*)alloc((size_t)N_NODES * NCLASS * 2);
    bfbits* h_b    = (bfbits*)alloc((size_t)N_NODES * NCLASS * 2);
    float*  hidden = (float*) alloc((size_t)N_NODES * NCLASS * 4);

    // --- graph preprocessing ---
    init_kernel<<<(N_NODES + 255) / 256, 256, 0, stream>>>(degi, cursor, N_NODES);
    count_kernel<<<(N_EDGES + 255) / 256, 256, 0, stream>>>(col, degi, N_EDGES);
    dinv_kernel<<<(N_NODES + 255) / 256, 256, 0, stream>>>(degi, dinv, N_NODES);
    scan_kernel<<<1, 1024, 0, stream>>>(degi, offs, N_NODES);
    scatter_kernel<<<(N_EDGES + 255) / 256, 256, 0, stream>>>(row, col, dinv, offs, cursor,
                                                              edges, N_EDGES);

    // --- MLP ---
    dim3 g1((N_NODES + 63) / 64, HIDDEN / 64);
    sgemm_relu<<<g1, 256, 0, stream>>>(x, W1, b1, h_mlp, N_NODES);
    dim3 g2((N_NODES + 63) / 64, 1);
    sgemm_dual<<<g2, 256, 0, stream>>>(h_mlp, W2, b2, h_a, hidden, temp, N_NODES);

    // --- GPR propagation: 10 hops ---
    int pgrid = (N_NODES * 64 + 255) / 256;
    for (int k = 0; k < K_HOPS; ++k) {
        bfbits* hi = (k & 1) ? h_b : h_a;
        bfbits* ho = (k & 1) ? h_a : h_b;
        propagate_kernel<<<pgrid, 256, 0, stream>>>(offs, edges, dinv, hi, ho, hidden,
                                                    temp, k + 1, N_NODES);
    }

    // --- log_softmax ---
    logsoftmax_kernel<<<pgrid, 256, 0, stream>>>(hidden, out, N_NODES);
}

// Round 3
// 1698.471 us; speedup vs baseline: 2.3259x; 1.2900x over previous
//
#include <hip/hip_runtime.h>
#include <hip/hip_bf16.h>
#include <math.h>

#define N_NODES 100000
#define N_EDGES 3200000
#define NFEAT   512
#define HIDDEN  256
#define NCLASS  64
#define K_HOPS  10

typedef unsigned short bfbits;
typedef __attribute__((ext_vector_type(8))) short short8x;   // 8 bf16 (4 VGPRs)
typedef __attribute__((ext_vector_type(4))) float float4x;   // MFMA C/D

__device__ __forceinline__ float bf2f(bfbits u) {
    union { unsigned int i; float f; } v; v.i = ((unsigned int)u) << 16; return v.f;
}
__device__ __forceinline__ bfbits f2bf(float f) {
    union { float f; unsigned int i; } v; v.f = f;
    unsigned int b = v.i + 0x7FFFu + ((v.i >> 16) & 1u);   // round-to-nearest-even
    return (bfbits)(b >> 16);
}
__device__ __forceinline__ float2 unpack2(unsigned int u) {
    float2 r;
    union { unsigned int i; float f; } a, b;
    a.i = (u & 0xFFFFu) << 16; b.i = u & 0xFFFF0000u;
    r.x = a.f; r.y = b.f; return r;
}
__device__ __forceinline__ unsigned int pack2(float x, float y) {
    return ((unsigned int)f2bf(x)) | (((unsigned int)f2bf(y)) << 16);
}

// ---------------------------------------------------------------------------
// Graph preprocessing
// ---------------------------------------------------------------------------

__global__ void init_kernel(int* __restrict__ degi, int* __restrict__ cursor, int n) {
    int i = blockIdx.x * blockDim.x + threadIdx.x;
    if (i < n) { degi[i] = 1; cursor[i] = 0; }
}

__global__ void count_kernel(const int* __restrict__ col, int* __restrict__ degi, int e) {
    int i = blockIdx.x * blockDim.x + threadIdx.x;
    if (i < e) atomicAdd(&degi[col[i]], 1);
}

__global__ void dinv_kernel(const int* __restrict__ degi, float* __restrict__ dinv, int n) {
    int i = blockIdx.x * blockDim.x + threadIdx.x;
    if (i < n) dinv[i] = rsqrtf((float)degi[i]);
}

__global__ void scan_kernel(const int* __restrict__ degi, int* __restrict__ offs, int n) {
    __shared__ int part[1024];
    int tid = threadIdx.x;
    int chunk = (n + 1023) / 1024;
    int beg = tid * chunk;
    int end = min(beg + chunk, n);
    int s = 0;
    for (int i = beg; i < end; ++i) s += degi[i] - 1;
    part[tid] = s;
    __syncthreads();
    for (int d = 1; d < 1024; d <<= 1) {
        int v = (tid >= d) ? part[tid - d] : 0;
        __syncthreads();
        part[tid] += v;
        __syncthreads();
    }
    int run = (tid > 0) ? part[tid - 1] : 0;
    for (int i = beg; i < end; ++i) { offs[i] = run; run += degi[i] - 1; }
    if (tid == 1023) offs[n] = part[1023];
}

__global__ void scatter_kernel(const int* __restrict__ row, const int* __restrict__ col,
                               const float* __restrict__ dinv,
                               const int* __restrict__ offs, int* __restrict__ cursor,
                               int2* __restrict__ edges, int e) {
    int i = blockIdx.x * blockDim.x + threadIdx.x;
    if (i < e) {
        int c = col[i];
        int r = row[i];
        int p = offs[c] + atomicAdd(&cursor[c], 1);
        edges[p] = make_int2(r, __float_as_int(dinv[r] * dinv[c]));
    }
}

// ---------------------------------------------------------------------------
// Transpose + cast fp32 [K][N] -> bf16 [N][K]
// ---------------------------------------------------------------------------
__global__ __launch_bounds__(256) void transpose_cast(const float* __restrict__ src,
                                                      bfbits* __restrict__ dst,
                                                      int K, int N) {
    __shared__ float tile[32][33];
    int kt = blockIdx.x * 32, nt = blockIdx.y * 32;
    int c = threadIdx.x & 31, r0 = threadIdx.x >> 5;  // 8 rows at a time
#pragma unroll
    for (int i = 0; i < 4; ++i) {
        int r = r0 + i * 8;
        tile[r][c] = src[(size_t)(kt + r) * N + nt + c];
    }
    __syncthreads();
#pragma unroll
    for (int i = 0; i < 4; ++i) {
        int r = r0 + i * 8;  // output row within n-tile
        dst[(size_t)(nt + r) * K + kt + c] = f2bf(tile[c][r]);
    }
}

// ---------------------------------------------------------------------------
// GEMM1 (MFMA bf16): h_mlp[node][f] = relu(x @ W1 + b1), output bf16
// A-operand = W1T tile (features x k), B-operand = x tile (k x nodes)
// Block: 128 nodes x 256 feats, 512 threads (8 waves, wave = 64f x 64n)
// ---------------------------------------------------------------------------
#define LDP 40   // padded LDS row stride in bf16 elems (80 B; 2-way max bank alias)

__global__ __launch_bounds__(512) void gemm1_mfma(const float* __restrict__ X,
                                                  const bfbits* __restrict__ W1T,
                                                  const float* __restrict__ bias,
                                                  bfbits* __restrict__ H, int M) {
    __shared__ short x_lds[128 * LDP];
    __shared__ short w_lds[256 * LDP];
    int tid = threadIdx.x;
    int wave = tid >> 6, lane = tid & 63;
    int l15 = lane & 15, quad = lane >> 4;
    int fslot = wave & 3, nslot = wave >> 2;
    int m0 = blockIdx.x * 128;

    float4x acc[4][4];
#pragma unroll
    for (int i = 0; i < 4; ++i)
#pragma unroll
        for (int j = 0; j < 4; ++j) acc[i][j] = (float4x){0.f, 0.f, 0.f, 0.f};

    for (int kb = 0; kb < NFEAT; kb += 32) {
        // stage x tile: 128 nodes x 32 k fp32 -> bf16 LDS
#pragma unroll
        for (int c = 0; c < 2; ++c) {
            int qid = tid + c * 512;          // 0..1023
            int node = qid >> 3;              // 0..127
            int k0 = (qid & 7) * 4;
            int row = m0 + node;
            float4 v = make_float4(0.f, 0.f, 0.f, 0.f);
            if (row < M) v = *reinterpret_cast<const float4*>(X + (size_t)row * NFEAT + kb + k0);
            ushort4 u;
            u.x = f2bf(v.x); u.y = f2bf(v.y); u.z = f2bf(v.z); u.w = f2bf(v.w);
            *reinterpret_cast<ushort4*>(&x_lds[node * LDP + k0]) = u;
        }
        // stage W1T tile: 256 feats x 32 k bf16
#pragma unroll
        for (int c = 0; c < 2; ++c) {
            int qid = tid + c * 512;          // 0..1023
            int feat = qid >> 2;              // 0..255
            int k0 = (qid & 3) * 8;
            uint4 w = *reinterpret_cast<const uint4*>(W1T + (size_t)feat * NFEAT + kb + k0);
            *reinterpret_cast<uint4*>(&w_lds[feat * LDP + k0]) = w;
        }
        __syncthreads();
        short8x af[4], bf[4];
#pragma unroll
        for (int t = 0; t < 4; ++t) {
            af[t] = *reinterpret_cast<const short8x*>(&w_lds[(fslot * 64 + t * 16 + l15) * LDP + quad * 8]);
            bf[t] = *reinterpret_cast<const short8x*>(&x_lds[(nslot * 64 + t * 16 + l15) * LDP + quad * 8]);
        }
#pragma unroll
        for (int ft = 0; ft < 4; ++ft)
#pragma unroll
            for (int nt = 0; nt < 4; ++nt)
                acc[ft][nt] = __builtin_amdgcn_mfma_f32_16x16x32_bf16(af[ft], bf[nt], acc[ft][nt], 0, 0, 0);
        __syncthreads();
    }
    // epilogue: D col = node, row = feature; 4 consecutive feats per lane
#pragma unroll
    for (int ft = 0; ft < 4; ++ft) {
        int f = fslot * 64 + ft * 16 + quad * 4;
        float4 b = *reinterpret_cast<const float4*>(bias + f);
#pragma unroll
        for (int nt = 0; nt < 4; ++nt) {
            int node = m0 + nslot * 64 + nt * 16 + l15;
            if (node >= M) continue;
            float4x a = acc[ft][nt];
            ushort4 u;
            u.x = f2bf(fmaxf(a.x + b.x, 0.f));
            u.y = f2bf(fmaxf(a.y + b.y, 0.f));
            u.z = f2bf(fmaxf(a.z + b.z, 0.f));
            u.w = f2bf(fmaxf(a.w + b.w, 0.f));
            *reinterpret_cast<ushort4*>(H + (size_t)node * HIDDEN + f) = u;
        }
    }
}

// ---------------------------------------------------------------------------
// GEMM2 (MFMA bf16): h0 = h_mlp @ W2 + b2 (bf16), hidden = temp[0]*h0 (fp32)
// Block: 256 nodes x 64 feats, 256 threads (4 waves, wave = 64f x 64n)
// ---------------------------------------------------------------------------
__global__ __launch_bounds__(256) void gemm2_mfma(const bfbits* __restrict__ Hm,
                                                  const bfbits* __restrict__ W2T,
                                                  const float* __restrict__ bias,
                                                  bfbits* __restrict__ h0,
                                                  float* __restrict__ hidden,
                                                  const float* __restrict__ temp, int M) {
    __shared__ short h_lds[256 * LDP];
    __shared__ short w_lds[64 * LDP];
    int tid = threadIdx.x;
    int wave = tid >> 6, lane = tid & 63;
    int l15 = lane & 15, quad = lane >> 4;
    int nslot = wave;
    int m0 = blockIdx.x * 256;

    float4x acc[4][4];
#pragma unroll
    for (int i = 0; i < 4; ++i)
#pragma unroll
        for (int j = 0; j < 4; ++j) acc[i][j] = (float4x){0.f, 0.f, 0.f, 0.f};

    for (int kb = 0; kb < HIDDEN; kb += 32) {
        // stage h tile: 256 nodes x 32 k bf16
#pragma unroll
        for (int c = 0; c < 4; ++c) {
            int qid = tid + c * 256;          // 0..1023
            int node = qid >> 2;              // 0..255
            int k0 = (qid & 3) * 8;
            int row = m0 + node;
            uint4 v = make_uint4(0u, 0u, 0u, 0u);
            if (row < M) v = *reinterpret_cast<const uint4*>(Hm + (size_t)row * HIDDEN + kb + k0);
            *reinterpret_cast<uint4*>(&h_lds[node * LDP + k0]) = v;
        }
        // stage W2T tile: 64 feats x 32 k
        {
            int feat = tid >> 2;
            int k0 = (tid & 3) * 8;
            uint4 w = *reinterpret_cast<const uint4*>(W2T + (size_t)feat * HIDDEN + kb + k0);
            *reinterpret_cast<uint4*>(&w_lds[feat * LDP + k0]) = w;
        }
        __syncthreads();
        short8x af[4], bf[4];
#pragma unroll
        for (int t = 0; t < 4; ++t) {
            af[t] = *reinterpret_cast<const short8x*>(&w_lds[(t * 16 + l15) * LDP + quad * 8]);
            bf[t] = *reinterpret_cast<const short8x*>(&h_lds[(nslot * 64 + t * 16 + l15) * LDP + quad * 8]);
        }
#pragma unroll
        for (int ft = 0; ft < 4; ++ft)
#pragma unroll
            for (int nt = 0; nt < 4; ++nt)
                acc[ft][nt] = __builtin_amdgcn_mfma_f32_16x16x32_bf16(af[ft], bf[nt], acc[ft][nt], 0, 0, 0);
        __syncthreads();
    }
    float t0 = temp[0];
#pragma unroll
    for (int ft = 0; ft < 4; ++ft) {
        int f = ft * 16 + quad * 4;
        float4 b = *reinterpret_cast<const float4*>(bias + f);
#pragma unroll
        for (int nt = 0; nt < 4; ++nt) {
            int node = m0 + nslot * 64 + nt * 16 + l15;
            if (node >= M) continue;
            float4x a = acc[ft][nt];
            float4 v = make_float4(a.x + b.x, a.y + b.y, a.z + b.z, a.w + b.w);
            ushort4 u;
            u.x = f2bf(v.x); u.y = f2bf(v.y); u.z = f2bf(v.z); u.w = f2bf(v.w);
            *reinterpret_cast<ushort4*>(h0 + (size_t)node * NCLASS + f) = u;
            float4 hv = make_float4(t0 * v.x, t0 * v.y, t0 * v.z, t0 * v.w);
            *reinterpret_cast<float4*>(hidden + (size_t)node * NCLASS + f) = hv;
        }
    }
}

// ---------------------------------------------------------------------------
// GPR propagation: wave per node, lane owns 2 packed bf16 feats (uint),
// half-waves process edges e (half 0) and e+1 (half 1); unroll 4 pairs.
// ---------------------------------------------------------------------------
__global__ __launch_bounds__(256) void propagate_kernel(const int* __restrict__ offs,
                                                        const int2* __restrict__ edges,
                                                        const float* __restrict__ dinv,
                                                        const unsigned int* __restrict__ hin,
                                                        unsigned int* __restrict__ hout,
                                                        float* __restrict__ hidden,
                                                        const float* __restrict__ temp,
                                                        int kidx, int n) {
    int node = (blockIdx.x * blockDim.x + threadIdx.x) >> 6;
    int lane = threadIdx.x & 63;
    if (node >= n) return;
    int half = lane >> 5, sub = lane & 31;
    float tk = temp[kidx];
    int beg = offs[node], end = offs[node + 1];
    float di = dinv[node];
    float dd = di * di;
    unsigned int us = hin[(size_t)node * 32 + sub];
    float2 acc = make_float2(0.f, 0.f);
    if (half == 0) {
        float2 hv = unpack2(us);
        acc.x = dd * hv.x; acc.y = dd * hv.y;
    }
    int e = beg;
    for (; e + 8 <= end; e += 8) {
        int2 e0 = edges[e + 0 + half];
        int2 e1 = edges[e + 2 + half];
        int2 e2 = edges[e + 4 + half];
        int2 e3 = edges[e + 6 + half];
        unsigned int u0 = hin[(size_t)e0.x * 32 + sub];
        unsigned int u1 = hin[(size_t)e1.x * 32 + sub];
        unsigned int u2 = hin[(size_t)e2.x * 32 + sub];
        unsigned int u3 = hin[(size_t)e3.x * 32 + sub];
        float w0 = __int_as_float(e0.y), w1 = __int_as_float(e1.y);
        float w2 = __int_as_float(e2.y), w3 = __int_as_float(e3.y);
        float2 v0 = unpack2(u0), v1 = unpack2(u1), v2 = unpack2(u2), v3 = unpack2(u3);
        acc.x += w0 * v0.x + w1 * v1.x + w2 * v2.x + w3 * v3.x;
        acc.y += w0 * v0.y + w1 * v1.y + w2 * v2.y + w3 * v3.y;
    }
    for (; e + 2 <= end; e += 2) {
        int2 ed = edges[e + half];
        unsigned int u = hin[(size_t)ed.x * 32 + sub];
        float w = __int_as_float(ed.y);
        float2 v = unpack2(u);
        acc.x += w * v.x; acc.y += w * v.y;
    }
    if (e < end && half == 0) {
        int2 ed = edges[e];
        unsigned int u = hin[(size_t)ed.x * 32 + sub];
        float w = __int_as_float(ed.y);
        float2 v = unpack2(u);
        acc.x += w * v.x; acc.y += w * v.y;
    }
    // combine half-waves
    acc.x += __shfl_xor(acc.x, 32, 64);
    acc.y += __shfl_xor(acc.y, 32, 64);
    if (half == 0) {
        hout[(size_t)node * 32 + sub] = pack2(acc.x, acc.y);
        float2* hd = reinterpret_cast<float2*>(hidden + (size_t)node * 64 + 2 * sub);
        float2 old = *hd;
        old.x += tk * acc.x; old.y += tk * acc.y;
        *hd = old;
    }
}

// ---------------------------------------------------------------------------
__global__ __launch_bounds__(256) void logsoftmax_kernel(const float* __restrict__ hidden,
                                                         float* __restrict__ out, int n) {
    int node = (blockIdx.x * blockDim.x + threadIdx.x) >> 6;
    int lane = threadIdx.x & 63;
    if (node >= n) return;
    float v = hidden[(size_t)node * 64 + lane];
    float m = v;
#pragma unroll
    for (int o = 32; o > 0; o >>= 1) m = fmaxf(m, __shfl_xor(m, o, 64));
    float ex = expf(v - m);
    float s = ex;
#pragma unroll
    for (int o = 32; o > 0; o >>= 1) s += __shfl_xor(s, o, 64);
    out[(size_t)node * 64 + lane] = v - m - logf(s);
}

// ---------------------------------------------------------------------------

extern "C" void kernel_launch(void* const* d_in, const int* in_sizes, int n_in,
                              void* d_out, int out_size, void* d_ws, size_t ws_size,
                              hipStream_t stream) {
    const float* x    = (const float*)d_in[0];
    const int*   ei   = (const int*)d_in[1];
    const int*   row  = ei;
    const int*   col  = ei + N_EDGES;
    const float* W1   = (const float*)d_in[2];
    const float* b1   = (const float*)d_in[3];
    const float* W2   = (const float*)d_in[4];
    const float* b2   = (const float*)d_in[5];
    const float* temp = (const float*)d_in[6];
    float*       out  = (float*)d_out;

    char* ws = (char*)d_ws;
    size_t off = 0;
    auto alloc = [&](size_t bytes) -> void* {
        void* p = ws + off;
        off += (bytes + 255) & ~(size_t)255;
        return p;
    };
    int*    degi   = (int*)   alloc((size_t)N_NODES * 4);
    float*  dinv   = (float*) alloc((size_t)N_NODES * 4);
    int*    offs   = (int*)   alloc((size_t)(N_NODES + 1) * 4);
    int*    cursor = (int*)   alloc((size_t)N_NODES * 4);
    int2*   edges  = (int2*)  alloc((size_t)N_EDGES * 8);
    bfbits* W1T    = (bfbits*)alloc((size_t)HIDDEN * NFEAT * 2);
    bfbits* W2T    = (bfbits*)alloc((size_t)NCLASS * HIDDEN * 2);
    bfbits* h_mlp  = (bfbits*)alloc((size_t)N_NODES * HIDDEN * 2);
    bfbits* h_a    = (bfbits*)alloc((size_t)N_NODES * NCLASS * 2);
    bfbits* h_b    = (bfbits*)alloc((size_t)N_NODES * NCLASS * 2);
    float*  hidden = (float*) alloc((size_t)N_NODES * NCLASS * 4);

    // --- graph preprocessing ---
    init_kernel<<<(N_NODES + 255) / 256, 256, 0, stream>>>(degi, cursor, N_NODES);
    count_kernel<<<(N_EDGES + 255) / 256, 256, 0, stream>>>(col, degi, N_EDGES);
    dinv_kernel<<<(N_NODES + 255) / 256, 256, 0, stream>>>(degi, dinv, N_NODES);
    scan_kernel<<<1, 1024, 0, stream>>>(degi, offs, N_NODES);
    scatter_kernel<<<(N_EDGES + 255) / 256, 256, 0, stream>>>(row, col, dinv, offs, cursor,
                                                              edges, N_EDGES);

    // --- weight transpose+cast ---
    dim3 gt1(NFEAT / 32, HIDDEN / 32);
    transpose_cast<<<gt1, 256, 0, stream>>>(W1, W1T, NFEAT, HIDDEN);
    dim3 gt2(HIDDEN / 32, NCLASS / 32);
    transpose_cast<<<gt2, 256, 0, stream>>>(W2, W2T, HIDDEN, NCLASS);

    // --- MLP (bf16 MFMA) ---
    gemm1_mfma<<<(N_NODES + 127) / 128, 512, 0, stream>>>(x, W1T, b1, h_mlp, N_NODES);
    gemm2_mfma<<<(N_NODES + 255) / 256, 256, 0, stream>>>(h_mlp, W2T, b2, h_a, hidden,
                                                          temp, N_NODES);

    // --- GPR propagation: 10 hops ---
    int pgrid = (N_NODES * 64 + 255) / 256;
    for (int k = 0; k < K_HOPS; ++k) {
        bfbits* hi = (k & 1) ? h_b : h_a;
        bfbits* ho = (k & 1) ? h_a : h_b;
        propagate_kernel<<<pgrid, 256, 0, stream>>>(offs, edges, dinv,
                                                    (const unsigned int*)hi,
                                                    (unsigned int*)ho, hidden,
                                                    temp, k + 1, N_NODES);
    }

    // --- log_softmax ---
    logsoftmax_kernel<<<pgrid, 256, 0, stream>>>(hidden, out, N_NODES);
}

// Round 4
// 1503.957 us; speedup vs baseline: 2.6267x; 1.1293x over previous
//
#include <hip/hip_runtime.h>
#include <hip/hip_bf16.h>
#include <math.h>

#define N_NODES 100000
#define N_EDGES 3200000
#define NFEAT   512
#define HIDDEN  256
#define NCLASS  64
#define K_HOPS  10

typedef unsigned short bfbits;
typedef __attribute__((ext_vector_type(8))) short short8x;   // 8 bf16 (4 VGPRs)
typedef __attribute__((ext_vector_type(4))) float float4x;   // MFMA C/D

__device__ __forceinline__ float bf2f(bfbits u) {
    union { unsigned int i; float f; } v; v.i = ((unsigned int)u) << 16; return v.f;
}
__device__ __forceinline__ bfbits f2bf(float f) {
    union { float f; unsigned int i; } v; v.f = f;
    unsigned int b = v.i + 0x7FFFu + ((v.i >> 16) & 1u);   // round-to-nearest-even
    return (bfbits)(b >> 16);
}
__device__ __forceinline__ float2 unpack2(unsigned int u) {
    float2 r;
    union { unsigned int i; float f; } a, b;
    a.i = (u & 0xFFFFu) << 16; b.i = u & 0xFFFF0000u;
    r.x = a.f; r.y = b.f; return r;
}
__device__ __forceinline__ unsigned int pack2(float x, float y) {
    return ((unsigned int)f2bf(x)) | (((unsigned int)f2bf(y)) << 16);
}

// ---------------------------------------------------------------------------
// Graph preprocessing
// ---------------------------------------------------------------------------

__global__ void init_kernel(int* __restrict__ degi, int* __restrict__ cursor, int n) {
    int i = blockIdx.x * blockDim.x + threadIdx.x;
    if (i < n) { degi[i] = 1; cursor[i] = 0; }
}

__global__ void count_kernel(const int* __restrict__ col, int* __restrict__ degi, int e) {
    int i = blockIdx.x * blockDim.x + threadIdx.x;
    if (i < e) atomicAdd(&degi[col[i]], 1);
}

__global__ void dinv_kernel(const int* __restrict__ degi, float* __restrict__ dinv, int n) {
    int i = blockIdx.x * blockDim.x + threadIdx.x;
    if (i < n) dinv[i] = rsqrtf((float)degi[i]);
}

__global__ void scan_kernel(const int* __restrict__ degi, int* __restrict__ offs, int n) {
    __shared__ int part[1024];
    int tid = threadIdx.x;
    int chunk = (n + 1023) / 1024;
    int beg = tid * chunk;
    int end = min(beg + chunk, n);
    int s = 0;
    for (int i = beg; i < end; ++i) s += degi[i] - 1;
    part[tid] = s;
    __syncthreads();
    for (int d = 1; d < 1024; d <<= 1) {
        int v = (tid >= d) ? part[tid - d] : 0;
        __syncthreads();
        part[tid] += v;
        __syncthreads();
    }
    int run = (tid > 0) ? part[tid - 1] : 0;
    for (int i = beg; i < end; ++i) { offs[i] = run; run += degi[i] - 1; }
    if (tid == 1023) offs[n] = part[1023];
}

// edges carry ONLY the src index now (4B) — weights are folded into the
// g-substitution (g = dinv .* h), so propagation is a pure unweighted sum.
__global__ void scatter_kernel(const int* __restrict__ row, const int* __restrict__ col,
                               const int* __restrict__ offs, int* __restrict__ cursor,
                               int* __restrict__ srcs, int e) {
    int i = blockIdx.x * blockDim.x + threadIdx.x;
    if (i < e) {
        int c = col[i];
        int p = offs[c] + atomicAdd(&cursor[c], 1);
        srcs[p] = row[i];
    }
}

// ---------------------------------------------------------------------------
// Transpose + cast fp32 [K][N] -> bf16 [N][K]
// ---------------------------------------------------------------------------
__global__ __launch_bounds__(256) void transpose_cast(const float* __restrict__ src,
                                                      bfbits* __restrict__ dst,
                                                      int K, int N) {
    __shared__ float tile[32][33];
    int kt = blockIdx.x * 32, nt = blockIdx.y * 32;
    int c = threadIdx.x & 31, r0 = threadIdx.x >> 5;
#pragma unroll
    for (int i = 0; i < 4; ++i) {
        int r = r0 + i * 8;
        tile[r][c] = src[(size_t)(kt + r) * N + nt + c];
    }
    __syncthreads();
#pragma unroll
    for (int i = 0; i < 4; ++i) {
        int r = r0 + i * 8;
        dst[(size_t)(nt + r) * K + kt + c] = f2bf(tile[c][r]);
    }
}

// ---------------------------------------------------------------------------
// GEMM1 (MFMA bf16): h_mlp = relu(x @ W1 + b1), bf16 out
// ---------------------------------------------------------------------------
#define LDP 40   // padded LDS row stride in bf16 elems

__global__ __launch_bounds__(512) void gemm1_mfma(const float* __restrict__ X,
                                                  const bfbits* __restrict__ W1T,
                                                  const float* __restrict__ bias,
                                                  bfbits* __restrict__ H, int M) {
    __shared__ short x_lds[128 * LDP];
    __shared__ short w_lds[256 * LDP];
    int tid = threadIdx.x;
    int wave = tid >> 6, lane = tid & 63;
    int l15 = lane & 15, quad = lane >> 4;
    int fslot = wave & 3, nslot = wave >> 2;
    int m0 = blockIdx.x * 128;

    float4x acc[4][4];
#pragma unroll
    for (int i = 0; i < 4; ++i)
#pragma unroll
        for (int j = 0; j < 4; ++j) acc[i][j] = (float4x){0.f, 0.f, 0.f, 0.f};

    for (int kb = 0; kb < NFEAT; kb += 32) {
#pragma unroll
        for (int c = 0; c < 2; ++c) {
            int qid = tid + c * 512;
            int node = qid >> 3;
            int k0 = (qid & 7) * 4;
            int row = m0 + node;
            float4 v = make_float4(0.f, 0.f, 0.f, 0.f);
            if (row < M) v = *reinterpret_cast<const float4*>(X + (size_t)row * NFEAT + kb + k0);
            ushort4 u;
            u.x = f2bf(v.x); u.y = f2bf(v.y); u.z = f2bf(v.z); u.w = f2bf(v.w);
            *reinterpret_cast<ushort4*>(&x_lds[node * LDP + k0]) = u;
        }
#pragma unroll
        for (int c = 0; c < 2; ++c) {
            int qid = tid + c * 512;
            int feat = qid >> 2;
            int k0 = (qid & 3) * 8;
            uint4 w = *reinterpret_cast<const uint4*>(W1T + (size_t)feat * NFEAT + kb + k0);
            *reinterpret_cast<uint4*>(&w_lds[feat * LDP + k0]) = w;
        }
        __syncthreads();
        short8x af[4], bf[4];
#pragma unroll
        for (int t = 0; t < 4; ++t) {
            af[t] = *reinterpret_cast<const short8x*>(&w_lds[(fslot * 64 + t * 16 + l15) * LDP + quad * 8]);
            bf[t] = *reinterpret_cast<const short8x*>(&x_lds[(nslot * 64 + t * 16 + l15) * LDP + quad * 8]);
        }
#pragma unroll
        for (int ft = 0; ft < 4; ++ft)
#pragma unroll
            for (int nt = 0; nt < 4; ++nt)
                acc[ft][nt] = __builtin_amdgcn_mfma_f32_16x16x32_bf16(af[ft], bf[nt], acc[ft][nt], 0, 0, 0);
        __syncthreads();
    }
#pragma unroll
    for (int ft = 0; ft < 4; ++ft) {
        int f = fslot * 64 + ft * 16 + quad * 4;
        float4 b = *reinterpret_cast<const float4*>(bias + f);
#pragma unroll
        for (int nt = 0; nt < 4; ++nt) {
            int node = m0 + nslot * 64 + nt * 16 + l15;
            if (node >= M) continue;
            float4x a = acc[ft][nt];
            ushort4 u;
            u.x = f2bf(fmaxf(a.x + b.x, 0.f));
            u.y = f2bf(fmaxf(a.y + b.y, 0.f));
            u.z = f2bf(fmaxf(a.z + b.z, 0.f));
            u.w = f2bf(fmaxf(a.w + b.w, 0.f));
            *reinterpret_cast<ushort4*>(H + (size_t)node * HIDDEN + f) = u;
        }
    }
}

// ---------------------------------------------------------------------------
// GEMM2 (MFMA bf16): v = h_mlp @ W2 + b2
//   g0 = dinv*v (bf16, hop state);  S = (temp0/dinv)*v (fp32 accumulator)
// Final output will be dinv * S (fused into logsoftmax).
// ---------------------------------------------------------------------------
__global__ __launch_bounds__(256) void gemm2_mfma(const bfbits* __restrict__ Hm,
                                                  const bfbits* __restrict__ W2T,
                                                  const float* __restrict__ bias,
                                                  const float* __restrict__ dinv,
                                                  bfbits* __restrict__ g0,
                                                  float* __restrict__ S,
                                                  const float* __restrict__ temp, int M) {
    __shared__ short h_lds[256 * LDP];
    __shared__ short w_lds[64 * LDP];
    int tid = threadIdx.x;
    int wave = tid >> 6, lane = tid & 63;
    int l15 = lane & 15, quad = lane >> 4;
    int nslot = wave;
    int m0 = blockIdx.x * 256;

    float4x acc[4][4];
#pragma unroll
    for (int i = 0; i < 4; ++i)
#pragma unroll
        for (int j = 0; j < 4; ++j) acc[i][j] = (float4x){0.f, 0.f, 0.f, 0.f};

    for (int kb = 0; kb < HIDDEN; kb += 32) {
#pragma unroll
        for (int c = 0; c < 4; ++c) {
            int qid = tid + c * 256;
            int node = qid >> 2;
            int k0 = (qid & 3) * 8;
            int row = m0 + node;
            uint4 v = make_uint4(0u, 0u, 0u, 0u);
            if (row < M) v = *reinterpret_cast<const uint4*>(Hm + (size_t)row * HIDDEN + kb + k0);
            *reinterpret_cast<uint4*>(&h_lds[node * LDP + k0]) = v;
        }
        {
            int feat = tid >> 2;
            int k0 = (tid & 3) * 8;
            uint4 w = *reinterpret_cast<const uint4*>(W2T + (size_t)feat * HIDDEN + kb + k0);
            *reinterpret_cast<uint4*>(&w_lds[feat * LDP + k0]) = w;
        }
        __syncthreads();
        short8x af[4], bf[4];
#pragma unroll
        for (int t = 0; t < 4; ++t) {
            af[t] = *reinterpret_cast<const short8x*>(&w_lds[(t * 16 + l15) * LDP + quad * 8]);
            bf[t] = *reinterpret_cast<const short8x*>(&h_lds[(nslot * 64 + t * 16 + l15) * LDP + quad * 8]);
        }
#pragma unroll
        for (int ft = 0; ft < 4; ++ft)
#pragma unroll
            for (int nt = 0; nt < 4; ++nt)
                acc[ft][nt] = __builtin_amdgcn_mfma_f32_16x16x32_bf16(af[ft], bf[nt], acc[ft][nt], 0, 0, 0);
        __syncthreads();
    }
    float t0 = temp[0];
#pragma unroll
    for (int nt = 0; nt < 4; ++nt) {
        int node = m0 + nslot * 64 + nt * 16 + l15;
        if (node >= M) continue;
        float di = dinv[node];
        float s0 = t0 / di;
#pragma unroll
        for (int ft = 0; ft < 4; ++ft) {
            int f = ft * 16 + quad * 4;
            float4 b = *reinterpret_cast<const float4*>(bias + f);
            float4x a = acc[ft][nt];
            float4 v = make_float4(a.x + b.x, a.y + b.y, a.z + b.z, a.w + b.w);
            ushort4 u;
            u.x = f2bf(di * v.x); u.y = f2bf(di * v.y);
            u.z = f2bf(di * v.z); u.w = f2bf(di * v.w);
            *reinterpret_cast<ushort4*>(g0 + (size_t)node * NCLASS + f) = u;
            float4 sv = make_float4(s0 * v.x, s0 * v.y, s0 * v.z, s0 * v.w);
            *reinterpret_cast<float4*>(S + (size_t)node * NCLASS + f) = sv;
        }
    }
}

// ---------------------------------------------------------------------------
// GPR propagation (g-form): t[c] = g[c] + sum_{r->c} g[r]   (pure sum!)
//   g_out[c] = dinv[c]^2 * t[c]   (bf16);   S[c] += temp[k] * t[c]  (fp32)
// Wave per node; quarter-wave (16 lanes, uint2 = 4 bf16 feats) per edge:
// one gather instruction covers 4 edges (512B). Unroll 16 edges.
// ---------------------------------------------------------------------------
__global__ __launch_bounds__(256) void propagate_kernel(const int* __restrict__ offs,
                                                        const int* __restrict__ srcs,
                                                        const float* __restrict__ dinv,
                                                        const uint2* __restrict__ gin,
                                                        uint2* __restrict__ gout,
                                                        float* __restrict__ S,
                                                        const float* __restrict__ temp,
                                                        int kidx, int n) {
    int node = (blockIdx.x * blockDim.x + threadIdx.x) >> 6;
    int lane = threadIdx.x & 63;
    if (node >= n) return;
    int q = lane >> 4, sub = lane & 15;
    float tk = temp[kidx];
    int beg = offs[node], end = offs[node + 1];

    // self term on quarter 0
    uint2 gs = gin[(size_t)node * 16 + sub];
    float4 acc = make_float4(0.f, 0.f, 0.f, 0.f);
    if (q == 0) {
        float2 lo = unpack2(gs.x), hi = unpack2(gs.y);
        acc = make_float4(lo.x, lo.y, hi.x, hi.y);
    }

    int e = beg;
    for (; e + 16 <= end; e += 16) {
#pragma unroll
        for (int j = 0; j < 4; ++j) {
            int s = srcs[e + j * 4 + q];
            uint2 u = gin[(size_t)s * 16 + sub];
            float2 lo = unpack2(u.x), hi = unpack2(u.y);
            acc.x += lo.x; acc.y += lo.y; acc.z += hi.x; acc.w += hi.y;
        }
    }
    for (; e < end; e += 4) {
        int idx = e + q;
        int sidx = (idx < end) ? idx : e;
        int s = srcs[sidx];
        uint2 u = gin[(size_t)s * 16 + sub];
        if (idx < end) {
            float2 lo = unpack2(u.x), hi = unpack2(u.y);
            acc.x += lo.x; acc.y += lo.y; acc.z += hi.x; acc.w += hi.y;
        }
    }

    // reduce across the 4 quarter-waves
    acc.x += __shfl_xor(acc.x, 16, 64); acc.y += __shfl_xor(acc.y, 16, 64);
    acc.z += __shfl_xor(acc.z, 16, 64); acc.w += __shfl_xor(acc.w, 16, 64);
    acc.x += __shfl_xor(acc.x, 32, 64); acc.y += __shfl_xor(acc.y, 32, 64);
    acc.z += __shfl_xor(acc.z, 32, 64); acc.w += __shfl_xor(acc.w, 32, 64);

    if (q == 0) {
        float di = dinv[node];
        float dd = di * di;
        gout[(size_t)node * 16 + sub] =
            make_uint2(pack2(dd * acc.x, dd * acc.y), pack2(dd * acc.z, dd * acc.w));
        float4* Sp = reinterpret_cast<float4*>(S + (size_t)node * 64 + sub * 4);
        float4 sv = *Sp;
        sv.x += tk * acc.x; sv.y += tk * acc.y;
        sv.z += tk * acc.z; sv.w += tk * acc.w;
        *Sp = sv;
    }
}

// ---------------------------------------------------------------------------
// log_softmax over 64 classes; hidden = dinv[node] * S[node][lane]
// ---------------------------------------------------------------------------
__global__ __launch_bounds__(256) void logsoftmax_kernel(const float* __restrict__ S,
                                                         const float* __restrict__ dinv,
                                                         float* __restrict__ out, int n) {
    int node = (blockIdx.x * blockDim.x + threadIdx.x) >> 6;
    int lane = threadIdx.x & 63;
    if (node >= n) return;
    float v = dinv[node] * S[(size_t)node * 64 + lane];
    float m = v;
#pragma unroll
    for (int o = 32; o > 0; o >>= 1) m = fmaxf(m, __shfl_xor(m, o, 64));
    float ex = expf(v - m);
    float s = ex;
#pragma unroll
    for (int o = 32; o > 0; o >>= 1) s += __shfl_xor(s, o, 64);
    out[(size_t)node * 64 + lane] = v - m - logf(s);
}

// ---------------------------------------------------------------------------

extern "C" void kernel_launch(void* const* d_in, const int* in_sizes, int n_in,
                              void* d_out, int out_size, void* d_ws, size_t ws_size,
                              hipStream_t stream) {
    const float* x    = (const float*)d_in[0];
    const int*   ei   = (const int*)d_in[1];
    const int*   row  = ei;
    const int*   col  = ei + N_EDGES;
    const float* W1   = (const float*)d_in[2];
    const float* b1   = (const float*)d_in[3];
    const float* W2   = (const float*)d_in[4];
    const float* b2   = (const float*)d_in[5];
    const float* temp = (const float*)d_in[6];
    float*       out  = (float*)d_out;

    char* ws = (char*)d_ws;
    size_t off = 0;
    auto alloc = [&](size_t bytes) -> void* {
        void* p = ws + off;
        off += (bytes + 255) & ~(size_t)255;
        return p;
    };
    int*    degi   = (int*)   alloc((size_t)N_NODES * 4);
    float*  dinv   = (float*) alloc((size_t)N_NODES * 4);
    int*    offs   = (int*)   alloc((size_t)(N_NODES + 1) * 4);
    int*    cursor = (int*)   alloc((size_t)N_NODES * 4);
    int*    srcs   = (int*)   alloc((size_t)N_EDGES * 4);
    bfbits* W1T    = (bfbits*)alloc((size_t)HIDDEN * NFEAT * 2);
    bfbits* W2T    = (bfbits*)alloc((size_t)NCLASS * HIDDEN * 2);
    bfbits* h_mlp  = (bfbits*)alloc((size_t)N_NODES * HIDDEN * 2);
    bfbits* g_a    = (bfbits*)alloc((size_t)N_NODES * NCLASS * 2);
    bfbits* g_b    = (bfbits*)alloc((size_t)N_NODES * NCLASS * 2);
    float*  S      = (float*) alloc((size_t)N_NODES * NCLASS * 4);

    // --- graph preprocessing ---
    init_kernel<<<(N_NODES + 255) / 256, 256, 0, stream>>>(degi, cursor, N_NODES);
    count_kernel<<<(N_EDGES + 255) / 256, 256, 0, stream>>>(col, degi, N_EDGES);
    dinv_kernel<<<(N_NODES + 255) / 256, 256, 0, stream>>>(degi, dinv, N_NODES);
    scan_kernel<<<1, 1024, 0, stream>>>(degi, offs, N_NODES);
    scatter_kernel<<<(N_EDGES + 255) / 256, 256, 0, stream>>>(row, col, offs, cursor,
                                                              srcs, N_EDGES);

    // --- weight transpose+cast ---
    dim3 gt1(NFEAT / 32, HIDDEN / 32);
    transpose_cast<<<gt1, 256, 0, stream>>>(W1, W1T, NFEAT, HIDDEN);
    dim3 gt2(HIDDEN / 32, NCLASS / 32);
    transpose_cast<<<gt2, 256, 0, stream>>>(W2, W2T, HIDDEN, NCLASS);

    // --- MLP (bf16 MFMA) ---
    gemm1_mfma<<<(N_NODES + 127) / 128, 512, 0, stream>>>(x, W1T, b1, h_mlp, N_NODES);
    gemm2_mfma<<<(N_NODES + 255) / 256, 256, 0, stream>>>(h_mlp, W2T, b2, dinv, g_a, S,
                                                          temp, N_NODES);

    // --- GPR propagation: 10 hops ---
    int pgrid = (N_NODES * 64 + 255) / 256;
    for (int k = 0; k < K_HOPS; ++k) {
        bfbits* gi = (k & 1) ? g_b : g_a;
        bfbits* go = (k & 1) ? g_a : g_b;
        propagate_kernel<<<pgrid, 256, 0, stream>>>(offs, srcs, dinv,
                                                    (const uint2*)gi, (uint2*)go, S,
                                                    temp, k + 1, N_NODES);
    }

    // --- log_softmax (hidden = dinv * S fused) ---
    logsoftmax_kernel<<<pgrid, 256, 0, stream>>>(S, dinv, out, N_NODES);
}